// Round 9
// baseline (121.336 us; speedup 1.0000x reference)
//
#include <hip/hip_runtime.h>

// MLP: 64 × (Linear(5,5)+ReLU) then Linear(5,1), BATCH = 1048576 rows.
// fp32 VALU compute-bound, scalar v_fma_f32 (v_pk_fma_f32 has NO throughput
// gain on CDNA4: fp32 peak 157.3 TF == scalar SIMD rate — R3-R7's packed
// attempts were all scalarized by the compiler, correctly).
//
// R9: R3's amortization (4 rows/thread, weights in VGPRs shared across
// rows) + EXPLICIT 1-LAYER PREFETCH DOUBLE-BUFFER to kill the ~35%
// inter-layer load-latency stall seen at every occupancy so far:
//   prep kernel -> d_ws[64][32] floats (25 W j-major, 5 b, 2 pad) + 8 tail
//   Wn[8] <- float4 loads of layer l+1   (issued BEFORE layer l's math)
//   compute layer l from Wc[8]           (100 fma + 20 max = 240 cyc,
//                                         covers ~200 cyc L1/L2 latency)
//   Wc = Wn  (full unroll -> SSA rename, free)
// __launch_bounds__(256,4): 128-VGPR budget so Wc+Wn+h+a (~110) stay live.
// Per layer per thread: 120 VALU + 8 VMEM for 4 rows = 30 VALU/row (ideal).

#define MLP_DEPTH 64
#define MLP_D 5
#define ROWS 4

// d_ws layout: layer l at [l*32]: k<25 -> W[j*5+i]; 25..29 -> b[j]; 30,31 pad.
// Tail at [2048]: W_out[0..4], b_out, pad, pad. Total 2056 floats.
__global__ __launch_bounds__(256) void MLP_prep_kernel(
    const float* __restrict__ Ws, const float* __restrict__ bs,
    const float* __restrict__ W_out, const float* __restrict__ b_out,
    float* __restrict__ ws)
{
    const int idx = blockIdx.x * blockDim.x + threadIdx.x;
    if (idx < MLP_DEPTH * 32) {
        const int l = idx >> 5, k = idx & 31;
        float v = 0.0f;
        if (k < 25) v = Ws[l * 25 + k];
        else if (k < 30) v = bs[l * MLP_D + (k - 25)];
        ws[idx] = v;
    } else if (idx < MLP_DEPTH * 32 + 8) {
        const int k = idx - MLP_DEPTH * 32;
        float v = 0.0f;
        if (k < MLP_D) v = W_out[k];
        else if (k == MLP_D) v = b_out[0];
        ws[idx] = v;
    }
}

__global__ __launch_bounds__(256, 4) void MLP_89687507075104_kernel(
    const float* __restrict__ x,      // [n, 5]
    const float4* __restrict__ wq,    // prep'd, 8 float4 per layer + 2 tail
    float* __restrict__ out,          // [n]
    int n)
{
    const int t = blockIdx.x * blockDim.x + threadIdx.x;
    const long row0 = (long)t * ROWS;
    if (row0 >= n) return;

    // rows row0..row0+3 = 20 contiguous floats (80 B, 16B-aligned).
    const float4* xp = reinterpret_cast<const float4*>(x + row0 * MLP_D);
    const float4 q0 = xp[0], q1 = xp[1], q2 = xp[2], q3 = xp[3], q4 = xp[4];
    float h[ROWS][MLP_D];
    h[0][0]=q0.x; h[0][1]=q0.y; h[0][2]=q0.z; h[0][3]=q0.w; h[0][4]=q1.x;
    h[1][0]=q1.y; h[1][1]=q1.z; h[1][2]=q1.w; h[1][3]=q2.x; h[1][4]=q2.y;
    h[2][0]=q2.z; h[2][1]=q2.w; h[2][2]=q3.x; h[2][3]=q3.y; h[2][4]=q3.z;
    h[3][0]=q3.w; h[3][1]=q4.x; h[3][2]=q4.y; h[3][3]=q4.z; h[3][4]=q4.w;

    // Prologue: load layer 0's weights.
    float4 Wc[8], Wn[8];
#pragma unroll
    for (int m = 0; m < 8; ++m) Wc[m] = wq[m];

#pragma unroll
    for (int l = 0; l < MLP_DEPTH; ++l) {
        // Prefetch next layer BEFORE this layer's math (8 independent
        // dwordx4; vmcnt drains behind 240 cyc of fma).
        if (l + 1 < MLP_DEPTH) {
#pragma unroll
            for (int m = 0; m < 8; ++m) Wn[m] = wq[(l + 1) * 8 + m];
        }

        float W[32];
#pragma unroll
        for (int m = 0; m < 8; ++m) {
            W[4*m+0] = Wc[m].x; W[4*m+1] = Wc[m].y;
            W[4*m+2] = Wc[m].z; W[4*m+3] = Wc[m].w;
        }
        float a[ROWS][MLP_D];
#pragma unroll
        for (int r = 0; r < ROWS; ++r) {
#pragma unroll
            for (int j = 0; j < MLP_D; ++j) {
                // bias enters as the first fma's VOP3 addend — no init mov
                float acc = fmaf(h[r][0], W[j * MLP_D + 0], W[25 + j]);
#pragma unroll
                for (int i = 1; i < MLP_D; ++i)
                    acc = fmaf(h[r][i], W[j * MLP_D + i], acc);
                a[r][j] = acc;
            }
        }
#pragma unroll
        for (int r = 0; r < ROWS; ++r)
#pragma unroll
            for (int j = 0; j < MLP_D; ++j)
                h[r][j] = fmaxf(a[r][j], 0.0f);

        // Swap (SSA rename under full unroll — no movs).
#pragma unroll
        for (int m = 0; m < 8; ++m) Wc[m] = Wn[m];
    }

    // Output layer: Linear(5,1). Tail floats at wq[512], wq[513].
    const float4 c0 = wq[MLP_DEPTH * 8 + 0];
    const float4 c1 = wq[MLP_DEPTH * 8 + 1];
    const float wo0 = c0.x, wo1 = c0.y, wo2 = c0.z, wo3 = c0.w;
    const float wo4 = c1.x, bo = c1.y;
    float o[ROWS];
#pragma unroll
    for (int r = 0; r < ROWS; ++r) {
        float acc = fmaf(h[r][0], wo0, bo);
        acc = fmaf(h[r][1], wo1, acc);
        acc = fmaf(h[r][2], wo2, acc);
        acc = fmaf(h[r][3], wo3, acc);
        acc = fmaf(h[r][4], wo4, acc);
        o[r] = acc;
    }
    float4 ov;
    ov.x = o[0]; ov.y = o[1]; ov.z = o[2]; ov.w = o[3];
    *reinterpret_cast<float4*>(out + row0) = ov;
}

extern "C" void kernel_launch(void* const* d_in, const int* in_sizes, int n_in,
                              void* d_out, int out_size, void* d_ws, size_t ws_size,
                              hipStream_t stream) {
    const float* x     = (const float*)d_in[0];
    const float* Ws    = (const float*)d_in[1];
    const float* bs    = (const float*)d_in[2];
    const float* W_out = (const float*)d_in[3];
    const float* b_out = (const float*)d_in[4];
    float* out = (float*)d_out;
    float* ws  = (float*)d_ws;   // needs 2056*4 = 8224 B

    const int n = in_sizes[0] / MLP_D;  // batch rows (1048576)

    const int nprep = MLP_DEPTH * 32 + 8;
    MLP_prep_kernel<<<(nprep + 255) / 256, 256, 0, stream>>>(Ws, bs, W_out, b_out, ws);

    const int block = 256;
    const int threads_needed = (n + ROWS - 1) / ROWS;
    const int grid = (threads_needed + block - 1) / block;  // 1024
    MLP_89687507075104_kernel<<<grid, block, 0, stream>>>(
        x, reinterpret_cast<const float4*>(ws), out, n);
}